// Round 13
// baseline (309.707 us; speedup 1.0000x reference)
//
#include <hip/hip_runtime.h>
#include <hip/hip_fp16.h>

#define N_NODES 50000
#define N0_ 20000
#define N1_ 15000
#define N2_ 15000
#define E_EDGES 800000
#define H_ 128
#define C_ 64

#define PB0 ((N0_ + 63) / 64)              // 313
#define PB1 ((N1_ + 63) / 64)              // 235
#define PB2 ((N2_ + 63) / 64)              // 235
#define PB_TOTAL (PB0 + PB1 + PB2)         // 783
#define EB ((E_EDGES + 255) / 256)         // 3125
#define SB ((N_NODES + 255) / 256)         // 196

// Wt layout (halves): hi0[128*512] lo0 hi1[128*256] lo1 hi2[128*128] lo2
#define WT_HI0 0
#define WT_LO0 65536
#define WT_HI1 131072
#define WT_LO1 163840
#define WT_HI2 196608
#define WT_LO2 212992
#define WT_TOTAL 229376

typedef _Float16 half4_t __attribute__((ext_vector_type(4)));
typedef _Float16 half8_t __attribute__((ext_vector_type(8)));
typedef float f32x4 __attribute__((ext_vector_type(4)));

// ---- A-tile loaders for the vector GEMM: fp32 direct, fp16 -> fp32 convert ----
__device__ __forceinline__ float4 load_a4(const float* A, size_t idx) {
    return *reinterpret_cast<const float4*>(&A[idx]);
}
__device__ __forceinline__ float4 load_a4(const __half* A, size_t idx) {
    __half2 p0 = *reinterpret_cast<const __half2*>(&A[idx]);
    __half2 p1 = *reinterpret_cast<const __half2*>(&A[idx + 2]);
    float2 f0 = __half22float2(p0), f1 = __half22float2(p1);
    return make_float4(f0.x, f0.y, f1.x, f1.y);
}

// ---------------- vector GEMM block (64-row tile, R3/R8-proven): l1/l2 layers ----------

template <int TN, bool BIAS, bool RELU, bool SCALE, typename IT, typename OT>
__device__ __forceinline__ void gemm_block(
    const IT* __restrict__ A, const float* __restrict__ W,
    const float* __restrict__ bias, const float* __restrict__ rowscale,
    OT* __restrict__ out, int M, int K, int m0, float* As, float* Bs) {
    constexpr int NJ = TN / 32;
    constexpr int TN4 = TN / 4;
    int tid = threadIdx.x;
    int tx = tid & 31;
    int ty = tid >> 5;

    float acc[8][NJ];
#pragma unroll
    for (int i = 0; i < 8; i++)
#pragma unroll
        for (int j = 0; j < NJ; j++) acc[i][j] = 0.f;

    for (int k0 = 0; k0 < K; k0 += 32) {
#pragma unroll
        for (int t0 = 0; t0 < 2; t0++) {
            int t = tid + t0 * 256;
            int row = t >> 3;
            int c = t & 7;
            float4 v = make_float4(0.f, 0.f, 0.f, 0.f);
            if (m0 + row < M) v = load_a4(A, (size_t)(m0 + row) * K + k0 + c * 4);
            As[(c * 4 + 0) * 68 + row] = v.x;
            As[(c * 4 + 1) * 68 + row] = v.y;
            As[(c * 4 + 2) * 68 + row] = v.z;
            As[(c * 4 + 3) * 68 + row] = v.w;
        }
#pragma unroll
        for (int t0 = 0; t0 < 32 * TN4 / 256; t0++) {
            int t = tid + t0 * 256;
            int r = t / TN4;
            int c4 = t % TN4;
            *reinterpret_cast<float4*>(&Bs[r * TN + c4 * 4]) =
                *reinterpret_cast<const float4*>(&W[(size_t)(k0 + r) * TN + c4 * 4]);
        }
        __syncthreads();
#pragma unroll 8
        for (int k = 0; k < 32; k++) {
            float4 a0 = *reinterpret_cast<float4*>(&As[k * 68 + ty * 8]);
            float4 a1 = *reinterpret_cast<float4*>(&As[k * 68 + ty * 8 + 4]);
            float ar[8] = {a0.x, a0.y, a0.z, a0.w, a1.x, a1.y, a1.z, a1.w};
            float br[NJ];
#pragma unroll
            for (int j = 0; j < NJ; j++) br[j] = Bs[k * TN + tx + 32 * j];
#pragma unroll
            for (int i = 0; i < 8; i++)
#pragma unroll
                for (int j = 0; j < NJ; j++) acc[i][j] = fmaf(ar[i], br[j], acc[i][j]);
        }
        __syncthreads();
    }
#pragma unroll
    for (int i = 0; i < 8; i++) {
        int row = m0 + ty * 8 + i;
        if (row < M) {
            float sc = SCALE ? rowscale[row] : 1.f;
#pragma unroll
            for (int j = 0; j < NJ; j++) {
                float v = acc[i][j] + (BIAS ? bias[tx + 32 * j] : 0.f);
                if (RELU) v = fmaxf(v, 0.f);
                v *= sc;
                out[(size_t)row * TN + tx + 32 * j] = (OT)v;
            }
        }
    }
}

// ---------------- W pre-transpose + hi/lo split (one-time, 0.45MB) ----------------

__global__ __launch_bounds__(256) void wt_kernel(
    const float* __restrict__ W0, const float* __restrict__ W1, const float* __restrict__ W2,
    __half* __restrict__ Wt) {
    int t = blockIdx.x * 256 + threadIdx.x;
    const float* W;
    int K;
    size_t bh, bl;
    int idx;
    if (t < 65536) {
        W = W0; K = 512; bh = WT_HI0; bl = WT_LO0; idx = t;
    } else if (t < 98304) {
        W = W1; K = 256; bh = WT_HI1; bl = WT_LO1; idx = t - 65536;
    } else if (t < 114688) {
        W = W2; K = 128; bh = WT_HI2; bl = WT_LO2; idx = t - 98304;
    } else {
        return;
    }
    int n = idx & 127;
    int k = idx >> 7;
    float v = W[(size_t)k * 128 + n];
    __half hi = __float2half(v);
    __half lo = __float2half(v - __half2float(hi));
    Wt[bh + (size_t)n * K + k] = hi;
    Wt[bl + (size_t)n * K + k] = lo;
}

// ---------------- K1: MFMA split-fp16 projections || rank (2 atomics/edge) ----------
// Proj: 64x128 tile, 4 waves x 16 rows, mfma_f32_16x16x32_f16.
// A=A_hi+A_lo staged in LDS (stride 40 halves: write ~4-way trivial, frag reads
// land on 8 disjoint bank-quads = 2-way free). B frags read DIRECTLY from the
// pre-transposed Wt in global (L2-resident) -- no in-loop transpose, no B LDS.
// acc += Ah*Bh + Al*Bh + Ah*Bl (lo*lo dropped; fp32-equivalent, verified R12).

__global__ __launch_bounds__(256) void k1_proj_rank(
    const float* __restrict__ feat0, const float* __restrict__ feat1, const float* __restrict__ feat2,
    const __half* __restrict__ Wt,
    const float* __restrict__ b0, const float* __restrict__ b1, const float* __restrict__ b2,
    __half* __restrict__ h0h,
    const int* __restrict__ src, const int* __restrict__ dst,
    int* __restrict__ cnt, int* __restrict__ degO, int* __restrict__ rank) {
    __shared__ _Float16 smem[5120];   // Ah[64*40] Al[64*40] = 10KB
    int bid = blockIdx.x;
    int tid = threadIdx.x;
    if (bid < PB_TOTAL) {
        const float* A; const float* bp; const __half* WtH; const __half* WtL; int M, K, m0;
        if (bid < PB0) {
            A = feat0; bp = b0; WtH = Wt + WT_HI0; WtL = Wt + WT_LO0;
            M = N0_; K = 512; m0 = bid * 64;
        } else if (bid < PB0 + PB1) {
            A = feat1; bp = b1; WtH = Wt + WT_HI1; WtL = Wt + WT_LO1;
            M = N1_; K = 256; m0 = (bid - PB0) * 64;
        } else {
            A = feat2; bp = b2; WtH = Wt + WT_HI2; WtL = Wt + WT_LO2;
            M = N2_; K = 128; m0 = (bid - PB0 - PB1) * 64;
        }
        size_t obase = (bid < PB0) ? 0 : ((bid < PB0 + PB1) ? (size_t)N0_ * H_
                                                            : (size_t)(N0_ + N1_) * H_);
        _Float16* Ah = smem;
        _Float16* Al = smem + 2560;

        int wv = tid >> 6;
        int lane = tid & 63;
        int lm = lane & 15;
        int ks = lane >> 4;                 // 0..3

        f32x4 acc[8];
#pragma unroll
        for (int j = 0; j < 8; j++)
#pragma unroll
            for (int r = 0; r < 4; r++) acc[j][r] = 0.f;

        for (int k0 = 0; k0 < K; k0 += 32) {
            // stage A (64 x 32) hi/lo
#pragma unroll
            for (int t0 = 0; t0 < 2; t0++) {
                int idx = tid + t0 * 256;
                int row = idx >> 3;
                int c = idx & 7;
                float4 v = make_float4(0.f, 0.f, 0.f, 0.f);
                if (m0 + row < M)
                    v = *reinterpret_cast<const float4*>(&A[(size_t)(m0 + row) * K + k0 + c * 4]);
                _Float16 hx = (_Float16)v.x, hy = (_Float16)v.y;
                _Float16 hz = (_Float16)v.z, hw = (_Float16)v.w;
                half4_t hi = {hx, hy, hz, hw};
                half4_t lo = {(_Float16)(v.x - (float)hx), (_Float16)(v.y - (float)hy),
                              (_Float16)(v.z - (float)hz), (_Float16)(v.w - (float)hw)};
                *reinterpret_cast<half4_t*>(&Ah[row * 40 + c * 4]) = hi;
                *reinterpret_cast<half4_t*>(&Al[row * 40 + c * 4]) = lo;
            }
            __syncthreads();
            half8_t ah = *reinterpret_cast<half8_t*>(&Ah[(16 * wv + lm) * 40 + ks * 8]);
            half8_t al = *reinterpret_cast<half8_t*>(&Al[(16 * wv + lm) * 40 + ks * 8]);
#pragma unroll
            for (int j = 0; j < 8; j++) {
                size_t boff = (size_t)(16 * j + lm) * K + k0 + ks * 8;
                half8_t bh = *reinterpret_cast<const half8_t*>(WtH + boff);
                half8_t bl = *reinterpret_cast<const half8_t*>(WtL + boff);
                acc[j] = __builtin_amdgcn_mfma_f32_16x16x32_f16(ah, bh, acc[j], 0, 0, 0);
                acc[j] = __builtin_amdgcn_mfma_f32_16x16x32_f16(al, bh, acc[j], 0, 0, 0);
                acc[j] = __builtin_amdgcn_mfma_f32_16x16x32_f16(ah, bl, acc[j], 0, 0, 0);
            }
            __syncthreads();
        }
        // epilogue: D col=lane&15, row=(lane>>4)*4+reg (m89-verified)
#pragma unroll
        for (int j = 0; j < 8; j++) {
            int colg = 16 * j + lm;
            float bb = bp[colg];
#pragma unroll
            for (int r = 0; r < 4; r++) {
                int row = m0 + 16 * wv + ks * 4 + r;
                if (row < M) h0h[obase + (size_t)row * H_ + colg] = (__half)(acc[j][r] + bb);
            }
        }
    } else {
        int e = (bid - PB_TOTAL) * 256 + tid;
        if (e < E_EDGES) {
            rank[e] = atomicAdd(&cnt[dst[e]], 1);
            atomicAdd(&degO[src[e]], 1);
        }
    }
}

// ---------------- hierarchical scan + norms; fill merged into scan3 ----------------

__global__ __launch_bounds__(256) void scan1_kernel(
    const int* __restrict__ cnt, int* __restrict__ pre, int* __restrict__ blocksum) {
    __shared__ int buf[256];
    int t = threadIdx.x;
    int i = blockIdx.x * 256 + t;
    int tot = (i < N_NODES) ? cnt[i] : 0;
    buf[t] = tot;
    __syncthreads();
#pragma unroll
    for (int off = 1; off < 256; off <<= 1) {
        int v = (t >= off) ? buf[t - off] : 0;
        __syncthreads();
        buf[t] += v;
        __syncthreads();
    }
    if (i < N_NODES) pre[i] = buf[t] - tot;
    if (t == 255) blocksum[blockIdx.x] = buf[255];
}

__global__ __launch_bounds__(256) void scan2_kernel(
    const int* __restrict__ blocksum, int* __restrict__ blockoff, int* __restrict__ rowptr) {
    __shared__ int buf[256];
    int t = threadIdx.x;
    int v = (t < SB) ? blocksum[t] : 0;
    buf[t] = v;
    __syncthreads();
#pragma unroll
    for (int off = 1; off < 256; off <<= 1) {
        int u = (t >= off) ? buf[t - off] : 0;
        __syncthreads();
        buf[t] += u;
        __syncthreads();
    }
    if (t < SB) blockoff[t] = buf[t] - v;
    if (t == 255) rowptr[N_NODES] = buf[255];
}

__global__ __launch_bounds__(256) void scan3_fill_kernel(
    const int* __restrict__ cnt, const int* __restrict__ degO, const int* __restrict__ pre,
    const int* __restrict__ blockoff, int* __restrict__ rowptr,
    float* __restrict__ ns, float* __restrict__ nd,
    const int* __restrict__ src, const int* __restrict__ dst,
    const int* __restrict__ rank, int* __restrict__ col) {
    int bid = blockIdx.x;
    if (bid < SB) {
        int i = bid * 256 + threadIdx.x;
        if (i < N_NODES) {
            rowptr[i] = blockoff[bid] + pre[i];
            ns[i] = rsqrtf(fmaxf((float)degO[i], 1.0f));
            nd[i] = rsqrtf(fmaxf((float)cnt[i], 1.0f));
        }
    } else {
        int e = (bid - SB) * 256 + threadIdx.x;
        if (e < E_EDGES) {
            int d = dst[e];
            int rp = blockoff[d >> 8] + pre[d];
            col[rp + rank[e]] = src[e];
        }
    }
}

// ---------------- fp16-gather aggregation (DEPTH=2 proven shape) ----------------

template <int CH, int NSLOAD, int EPI, int OUTH>
__global__ __launch_bounds__(256) void agg_h_kernel(
    const __half* __restrict__ h, const int* __restrict__ rowptr,
    const int* __restrict__ col, const float* __restrict__ ns,
    const float* __restrict__ nd, const float* __restrict__ bias,
    void* __restrict__ out) {
    constexpr int L = CH / 8;
    constexpr int EPW = 64 / L;
    int node = blockIdx.x * 4 + (threadIdx.x >> 6);
    if (node >= N_NODES) return;
    int lane = threadIdx.x & 63;
    int li = lane & (L - 1);
    int g = lane / L;
    const uint4* __restrict__ h8 = (const uint4*)h;
    int beg = rowptr[node], end = rowptr[node + 1];
    float a0[8] = {0.f, 0.f, 0.f, 0.f, 0.f, 0.f, 0.f, 0.f};
    float a1[8] = {0.f, 0.f, 0.f, 0.f, 0.f, 0.f, 0.f, 0.f};
    union U8 { uint4 u; __half2 h2[4]; };
    int e = beg + g;
    for (; e + EPW < end; e += 2 * EPW) {
        int s0 = col[e], s1 = col[e + EPW];
        U8 u0, u1;
        u0.u = h8[(size_t)s0 * L + li];
        u1.u = h8[(size_t)s1 * L + li];
        float w0 = NSLOAD ? ns[s0] : 1.f;
        float w1 = NSLOAD ? ns[s1] : 1.f;
#pragma unroll
        for (int p = 0; p < 4; p++) {
            float2 f0 = __half22float2(u0.h2[p]);
            float2 f1 = __half22float2(u1.h2[p]);
            if (NSLOAD) {
                a0[2 * p] = fmaf(w0, f0.x, a0[2 * p]);
                a0[2 * p + 1] = fmaf(w0, f0.y, a0[2 * p + 1]);
                a1[2 * p] = fmaf(w1, f1.x, a1[2 * p]);
                a1[2 * p + 1] = fmaf(w1, f1.y, a1[2 * p + 1]);
            } else {
                a0[2 * p] += f0.x;
                a0[2 * p + 1] += f0.y;
                a1[2 * p] += f1.x;
                a1[2 * p + 1] += f1.y;
            }
        }
    }
    if (e < end) {
        int s = col[e];
        U8 u0;
        u0.u = h8[(size_t)s * L + li];
        float w0 = NSLOAD ? ns[s] : 1.f;
#pragma unroll
        for (int p = 0; p < 4; p++) {
            float2 f0 = __half22float2(u0.h2[p]);
            if (NSLOAD) {
                a0[2 * p] = fmaf(w0, f0.x, a0[2 * p]);
                a0[2 * p + 1] = fmaf(w0, f0.y, a0[2 * p + 1]);
            } else {
                a0[2 * p] += f0.x;
                a0[2 * p + 1] += f0.y;
            }
        }
    }
#pragma unroll
    for (int j = 0; j < 8; j++) {
        float v = a0[j] + a1[j];
#pragma unroll
        for (int off = 32; off >= L; off >>= 1) v += __shfl_xor(v, off);
        a0[j] = v;
    }
    if (lane < L) {
        float w = nd[node];
#pragma unroll
        for (int j = 0; j < 8; j++) a0[j] *= w;
        if (EPI == 1) {
            float sc = ns[node];
#pragma unroll
            for (int j = 0; j < 8; j++)
                a0[j] = fmaxf(a0[j] + bias[li * 8 + j], 0.f) * sc;
        } else if (EPI == 2) {
#pragma unroll
            for (int j = 0; j < 8; j++) a0[j] += bias[li * 8 + j];
        }
        if (OUTH) {
            union { uint4 u; __half hh[8]; } cv;
#pragma unroll
            for (int j = 0; j < 8; j++) cv.hh[j] = __float2half(a0[j]);
            ((uint4*)out)[(size_t)node * L + li] = cv.u;
        } else {
            float4* o4 = (float4*)out;
            o4[(size_t)node * (CH / 4) + li * 2] = make_float4(a0[0], a0[1], a0[2], a0[3]);
            o4[(size_t)node * (CH / 4) + li * 2 + 1] = make_float4(a0[4], a0[5], a0[6], a0[7]);
        }
    }
}

// ---------------- standalone vector GEMM (64-row tile) ----------------

template <int TN, bool BIAS, bool RELU, bool SCALE, typename IT, typename OT>
__global__ __launch_bounds__(256) void gemm_kernel(
    const IT* __restrict__ A, const float* __restrict__ W,
    const float* __restrict__ bias, const float* __restrict__ rowscale,
    OT* __restrict__ out, int M, int K) {
    __shared__ float As[32 * 68];
    __shared__ float Bs[32 * TN];
    gemm_block<TN, BIAS, RELU, SCALE, IT, OT>(A, W, bias, rowscale, out, M, K, blockIdx.x * 64, As, Bs);
}

// ---------------- launch ----------------

extern "C" void kernel_launch(void* const* d_in, const int* in_sizes, int n_in,
                              void* d_out, int out_size, void* d_ws, size_t ws_size,
                              hipStream_t stream) {
    const float* feat0 = (const float*)d_in[0];
    const float* feat1 = (const float*)d_in[1];
    const float* feat2 = (const float*)d_in[2];
    const float* W0 = (const float*)d_in[3];
    const float* b0 = (const float*)d_in[4];
    const float* W1 = (const float*)d_in[5];
    const float* b1 = (const float*)d_in[6];
    const float* W2 = (const float*)d_in[7];
    const float* b2 = (const float*)d_in[8];
    const float* bias_l0 = (const float*)d_in[9];
    const float* W_l1 = (const float*)d_in[10];
    const float* b_l1 = (const float*)d_in[11];
    const float* W_l2 = (const float*)d_in[12];
    const float* b_l2 = (const float*)d_in[13];
    const int* src = (const int*)d_in[14];
    const int* dst = (const int*)d_in[15];
    float* out = (float*)d_out;

    char* ws = (char*)d_ws;
    size_t off = 0;
    auto alloc = [&](size_t bytes) {
        size_t cur = off;
        off += (bytes + 255) & ~(size_t)255;
        return cur;
    };
    size_t Wt_off = alloc((size_t)WT_TOTAL * 2);        // transposed split W (fp16)
    size_t h0h_off = alloc((size_t)N_NODES * H_ * 2);   // proj out (fp16)
    size_t h1h_off = alloc((size_t)N_NODES * H_ * 2);   // agg0 out (fp16)
    size_t hAh_off = alloc((size_t)N_NODES * H_ * 2);   // agg1 out (fp16)
    size_t hBh_off = alloc((size_t)N_NODES * H_ * 2);   // gemm1 out (fp16)
    size_t h2h_off = alloc((size_t)N_NODES * C_ * 2);   // gemm2 out (fp16)
    size_t cnt_off = alloc((size_t)N_NODES * 4);        // zeroed each call
    size_t degO_off = alloc((size_t)N_NODES * 4);       // zeroed each call
    size_t ns_off = alloc((size_t)N_NODES * 4);
    size_t nd_off = alloc((size_t)N_NODES * 4);
    size_t rowptr_off = alloc((size_t)(N_NODES + 1) * 4);
    size_t rank_off = alloc((size_t)E_EDGES * 4);
    size_t col_off = alloc((size_t)E_EDGES * 4);
    size_t pre_off = alloc((size_t)N_NODES * 4);
    size_t bsum_off = alloc((size_t)SB * 4);
    size_t boff_off = alloc((size_t)SB * 4);

    __half* Wt = (__half*)(ws + Wt_off);
    __half* h0h = (__half*)(ws + h0h_off);
    __half* h1h = (__half*)(ws + h1h_off);
    __half* hAh = (__half*)(ws + hAh_off);
    __half* hBh = (__half*)(ws + hBh_off);
    __half* h2h = (__half*)(ws + h2h_off);
    int* cnt = (int*)(ws + cnt_off);
    int* degO = (int*)(ws + degO_off);
    float* ns = (float*)(ws + ns_off);
    float* nd = (float*)(ws + nd_off);
    int* rowptr = (int*)(ws + rowptr_off);
    int* rank = (int*)(ws + rank_off);
    int* col = (int*)(ws + col_off);
    int* pre = (int*)(ws + pre_off);
    int* bsum = (int*)(ws + bsum_off);
    int* boff = (int*)(ws + boff_off);

    hipMemsetAsync(ws + cnt_off, 0, ns_off - cnt_off, stream);  // cnt + degO

    // W transpose + hi/lo split (one-time per call, 0.45MB)
    wt_kernel<<<448, 256, 0, stream>>>(W0, W1, W2, Wt);
    // K1: MFMA split-fp16 projections || rank
    k1_proj_rank<<<PB_TOTAL + EB, 256, 0, stream>>>(
        feat0, feat1, feat2, Wt, b0, b1, b2, h0h, src, dst, cnt, degO, rank);
    // hierarchical scan; norms + col-fill merged into the third stage
    scan1_kernel<<<SB, 256, 0, stream>>>(cnt, pre, bsum);
    scan2_kernel<<<1, 256, 0, stream>>>(bsum, boff, rowptr);
    scan3_fill_kernel<<<SB + EB, 256, 0, stream>>>(
        cnt, degO, pre, boff, rowptr, ns, nd, src, dst, rank, col);

    const int AGB = (N_NODES + 3) / 4;
    // layer 0: fp16 gather (ns-weighted), +bias, relu, *ns -> fp16 h1
    agg_h_kernel<128, 1, 1, 1><<<AGB, 256, 0, stream>>>(h0h, rowptr, col, ns, nd, bias_l0, h1h);
    // layer 1: fp16 gather (pre-scaled) -> fp16 hAh; GEMM (fp16 in/out) + bias + relu, *ns
    agg_h_kernel<128, 0, 0, 1><<<AGB, 256, 0, stream>>>(h1h, rowptr, col, ns, nd, nullptr, hAh);
    gemm_kernel<128, true, true, true, __half, __half><<<(N_NODES + 63) / 64, 256, 0, stream>>>(
        hAh, W_l1, b_l1, ns, hBh, N_NODES, 128);
    // layer 2 reordered: GEMM first (fp16 in/out, no bias), then 64-ch fp16 agg + bias
    gemm_kernel<64, false, false, false, __half, __half><<<(N_NODES + 63) / 64, 256, 0, stream>>>(
        hBh, W_l2, nullptr, nullptr, h2h, N_NODES, 128);
    agg_h_kernel<64, 0, 2, 0><<<AGB, 256, 0, stream>>>(h2h, rowptr, col, ns, nd, b_l2, out);
}

// Round 14
// 272.663 us; speedup vs baseline: 1.1359x; 1.1359x over previous
//
#include <hip/hip_runtime.h>
#include <hip/hip_fp16.h>

#define N_NODES 50000
#define N0_ 20000
#define N1_ 15000
#define N2_ 15000
#define E_EDGES 800000
#define H_ 128
#define C_ 64

#define PB0 ((N0_ + 63) / 64)              // 313
#define PB1 ((N1_ + 63) / 64)              // 235
#define PB2 ((N2_ + 63) / 64)              // 235
#define PB_TOTAL (PB0 + PB1 + PB2)         // 783
#define EB ((E_EDGES + 255) / 256)         // 3125
#define SB ((N_NODES + 255) / 256)         // 196

// Wt2: h2-interleaved weights, layout [k2][n] where element = (W[2k2][n], W[2k2+1][n])
#define WT2_0 0          // W0: 256 k2 x 128
#define WT2_1 32768      // W1: 128 k2 x 128
#define WT2_2 49152      // W2: 64 k2 x 128
#define WT2_L1 57344     // W_l1: 64 k2 x 128
#define WT2_L2 65536     // W_l2: 64 k2 x 64
#define WT2_TOTAL 69632

typedef _Float16 h2_t __attribute__((ext_vector_type(2)));

__device__ __forceinline__ float fdot2f(h2_t a, h2_t b, float c) {
#if __has_builtin(__builtin_amdgcn_fdot2)
    return __builtin_amdgcn_fdot2(a, b, c, false);
#else
    return fmaf((float)a[0], (float)b[0], fmaf((float)a[1], (float)b[1], c));
#endif
}

// ---------------- W -> interleaved-half2 pre-pass (one-time, 0.28MB out) ----------------

__global__ __launch_bounds__(256) void wt2_kernel(
    const float* __restrict__ W0, const float* __restrict__ W1, const float* __restrict__ W2,
    const float* __restrict__ Wl1, const float* __restrict__ Wl2,
    h2_t* __restrict__ Wt2) {
    int t = blockIdx.x * 256 + threadIdx.x;
    if (t >= WT2_TOTAL) return;
    const float* W;
    int rel, NW;
    if (t < WT2_1) { W = W0; rel = t; NW = 128; }
    else if (t < WT2_2) { W = W1; rel = t - WT2_1; NW = 128; }
    else if (t < WT2_L1) { W = W2; rel = t - WT2_2; NW = 128; }
    else if (t < WT2_L2) { W = Wl1; rel = t - WT2_L1; NW = 128; }
    else { W = Wl2; rel = t - WT2_L2; NW = 64; }
    int k2 = rel / NW;
    int n = rel % NW;
    h2_t p = {(_Float16)W[(size_t)(2 * k2) * NW + n], (_Float16)W[(size_t)(2 * k2 + 1) * NW + n]};
    Wt2[t] = p;
}

// ---------------- A-tile stagers (transposed half2: As2[k2*68 + row]) ----------------

__device__ __forceinline__ void stage_a_tile(const float* __restrict__ A, h2_t* As2,
                                             int M, int K, int m0, int k0, int tid) {
#pragma unroll
    for (int t0 = 0; t0 < 2; t0++) {
        int idx = tid + t0 * 256;
        int row = idx >> 3;
        int c = idx & 7;
        float4 v = make_float4(0.f, 0.f, 0.f, 0.f);
        if (m0 + row < M)
            v = *reinterpret_cast<const float4*>(&A[(size_t)(m0 + row) * K + k0 + c * 4]);
        h2_t p0 = {(_Float16)v.x, (_Float16)v.y};
        h2_t p1 = {(_Float16)v.z, (_Float16)v.w};
        As2[(c * 2) * 68 + row] = p0;
        As2[(c * 2 + 1) * 68 + row] = p1;
    }
}

__device__ __forceinline__ void stage_a_tile(const __half* __restrict__ A, h2_t* As2,
                                             int M, int K, int m0, int k0, int tid) {
    int row = tid >> 2;
    int c = tid & 3;
    union { uint4 u; h2_t p[4]; } v;
    v.u = make_uint4(0, 0, 0, 0);
    if (m0 + row < M)
        v.u = *reinterpret_cast<const uint4*>(&A[(size_t)(m0 + row) * K + k0 + c * 8]);
#pragma unroll
    for (int i = 0; i < 4; i++) As2[(c * 4 + i) * 68 + row] = v.p[i];
}

// ---------------- dot2 GEMM block (64-row tile, same proven tiling/banking) -----------
// A transposed in LDS as half2 (stride 68: A-frag reads broadcast, conflict-free).
// B staged by LINEAR copy from pre-interleaved Wt2 (no transpose, conflict-free);
// inner B reads lane-stride-1 broadcast (conflict-free). fdot2 = 2 MAC/instr, fp32 acc.

template <int TN, bool BIAS, bool RELU, bool SCALE, typename IT, typename OT>
__device__ __forceinline__ void gemm_block_h(
    const IT* __restrict__ A, const h2_t* __restrict__ Wt2,
    const float* __restrict__ bias, const float* __restrict__ rowscale,
    OT* __restrict__ out, int M, int K, int m0, h2_t* As2, h2_t* Bs2) {
    constexpr int NJ = TN / 32;
    int tid = threadIdx.x;
    int tx = tid & 31;
    int ty = tid >> 5;

    float acc[8][NJ];
#pragma unroll
    for (int i = 0; i < 8; i++)
#pragma unroll
        for (int j = 0; j < NJ; j++) acc[i][j] = 0.f;

    for (int k0 = 0; k0 < K; k0 += 32) {
        stage_a_tile(A, As2, M, K, m0, k0, tid);
        // stage B: linear copy of 16 x TN half2 from Wt2
        {
            const uint4* g = reinterpret_cast<const uint4*>(Wt2 + (size_t)(k0 / 2) * TN);
            uint4* l = reinterpret_cast<uint4*>(Bs2);
            constexpr int CNT = 16 * TN / 4;     // uint4 count (128->512, 64->256)
#pragma unroll
            for (int t0 = 0; t0 < CNT / 256; t0++) l[tid + t0 * 256] = g[tid + t0 * 256];
        }
        __syncthreads();
#pragma unroll
        for (int k2 = 0; k2 < 16; k2++) {
            union { uint4 u; h2_t p[4]; } ua, ub;
            ua.u = *reinterpret_cast<uint4*>(&As2[k2 * 68 + ty * 8]);
            ub.u = *reinterpret_cast<uint4*>(&As2[k2 * 68 + ty * 8 + 4]);
            h2_t ap[8] = {ua.p[0], ua.p[1], ua.p[2], ua.p[3],
                          ub.p[0], ub.p[1], ub.p[2], ub.p[3]};
            h2_t bp[NJ];
#pragma unroll
            for (int j = 0; j < NJ; j++) bp[j] = Bs2[k2 * TN + tx + 32 * j];
#pragma unroll
            for (int i = 0; i < 8; i++)
#pragma unroll
                for (int j = 0; j < NJ; j++) acc[i][j] = fdot2f(ap[i], bp[j], acc[i][j]);
        }
        __syncthreads();
    }
#pragma unroll
    for (int i = 0; i < 8; i++) {
        int row = m0 + ty * 8 + i;
        if (row < M) {
            float sc = SCALE ? rowscale[row] : 1.f;
#pragma unroll
            for (int j = 0; j < NJ; j++) {
                float v = acc[i][j] + (BIAS ? bias[tx + 32 * j] : 0.f);
                if (RELU) v = fmaxf(v, 0.f);
                v *= sc;
                out[(size_t)row * TN + tx + 32 * j] = (OT)v;
            }
        }
    }
}

// ---------------- K1: dot2 projections || rank (2 atomics/edge) ----------------

__global__ __launch_bounds__(256) void k1_proj_rank(
    const float* __restrict__ feat0, const float* __restrict__ feat1, const float* __restrict__ feat2,
    const h2_t* __restrict__ Wt2,
    const float* __restrict__ b0, const float* __restrict__ b1, const float* __restrict__ b2,
    __half* __restrict__ h0h,
    const int* __restrict__ src, const int* __restrict__ dst,
    int* __restrict__ cnt, int* __restrict__ degO, int* __restrict__ rank) {
    __shared__ h2_t As2[16 * 68];
    __shared__ h2_t Bs2[16 * 128];
    int bid = blockIdx.x;
    if (bid < PB_TOTAL) {
        const float* A; const float* bp; const h2_t* Wp; int M, K, m0;
        size_t obase;
        if (bid < PB0) {
            A = feat0; bp = b0; Wp = Wt2 + WT2_0; M = N0_; K = 512; m0 = bid * 64; obase = 0;
        } else if (bid < PB0 + PB1) {
            A = feat1; bp = b1; Wp = Wt2 + WT2_1; M = N1_; K = 256; m0 = (bid - PB0) * 64;
            obase = (size_t)N0_ * H_;
        } else {
            A = feat2; bp = b2; Wp = Wt2 + WT2_2; M = N2_; K = 128; m0 = (bid - PB0 - PB1) * 64;
            obase = (size_t)(N0_ + N1_) * H_;
        }
        gemm_block_h<128, true, false, false, float, __half>(
            A, Wp, bp, nullptr, h0h + obase, M, K, m0, As2, Bs2);
    } else {
        int e = (bid - PB_TOTAL) * 256 + threadIdx.x;
        if (e < E_EDGES) {
            rank[e] = atomicAdd(&cnt[dst[e]], 1);
            atomicAdd(&degO[src[e]], 1);
        }
    }
}

// ---------------- hierarchical scan + norms; fill merged into scan3 ----------------

__global__ __launch_bounds__(256) void scan1_kernel(
    const int* __restrict__ cnt, int* __restrict__ pre, int* __restrict__ blocksum) {
    __shared__ int buf[256];
    int t = threadIdx.x;
    int i = blockIdx.x * 256 + t;
    int tot = (i < N_NODES) ? cnt[i] : 0;
    buf[t] = tot;
    __syncthreads();
#pragma unroll
    for (int off = 1; off < 256; off <<= 1) {
        int v = (t >= off) ? buf[t - off] : 0;
        __syncthreads();
        buf[t] += v;
        __syncthreads();
    }
    if (i < N_NODES) pre[i] = buf[t] - tot;
    if (t == 255) blocksum[blockIdx.x] = buf[255];
}

__global__ __launch_bounds__(256) void scan2_kernel(
    const int* __restrict__ blocksum, int* __restrict__ blockoff, int* __restrict__ rowptr) {
    __shared__ int buf[256];
    int t = threadIdx.x;
    int v = (t < SB) ? blocksum[t] : 0;
    buf[t] = v;
    __syncthreads();
#pragma unroll
    for (int off = 1; off < 256; off <<= 1) {
        int u = (t >= off) ? buf[t - off] : 0;
        __syncthreads();
        buf[t] += u;
        __syncthreads();
    }
    if (t < SB) blockoff[t] = buf[t] - v;
    if (t == 255) rowptr[N_NODES] = buf[255];
}

__global__ __launch_bounds__(256) void scan3_fill_kernel(
    const int* __restrict__ cnt, const int* __restrict__ degO, const int* __restrict__ pre,
    const int* __restrict__ blockoff, int* __restrict__ rowptr,
    float* __restrict__ ns, float* __restrict__ nd,
    const int* __restrict__ src, const int* __restrict__ dst,
    const int* __restrict__ rank, int* __restrict__ col) {
    int bid = blockIdx.x;
    if (bid < SB) {
        int i = bid * 256 + threadIdx.x;
        if (i < N_NODES) {
            rowptr[i] = blockoff[bid] + pre[i];
            ns[i] = rsqrtf(fmaxf((float)degO[i], 1.0f));
            nd[i] = rsqrtf(fmaxf((float)cnt[i], 1.0f));
        }
    } else {
        int e = (bid - SB) * 256 + threadIdx.x;
        if (e < E_EDGES) {
            int d = dst[e];
            int rp = blockoff[d >> 8] + pre[d];
            col[rp + rank[e]] = src[e];
        }
    }
}

// ---------------- fp16-gather aggregation (R10-proven DEPTH=2 shape) ----------------

template <int CH, int NSLOAD, int EPI, int OUTH>
__global__ __launch_bounds__(256) void agg_h_kernel(
    const __half* __restrict__ h, const int* __restrict__ rowptr,
    const int* __restrict__ col, const float* __restrict__ ns,
    const float* __restrict__ nd, const float* __restrict__ bias,
    void* __restrict__ out) {
    constexpr int L = CH / 8;
    constexpr int EPW = 64 / L;
    int node = blockIdx.x * 4 + (threadIdx.x >> 6);
    if (node >= N_NODES) return;
    int lane = threadIdx.x & 63;
    int li = lane & (L - 1);
    int g = lane / L;
    const uint4* __restrict__ h8 = (const uint4*)h;
    int beg = rowptr[node], end = rowptr[node + 1];
    float a0[8] = {0.f, 0.f, 0.f, 0.f, 0.f, 0.f, 0.f, 0.f};
    float a1[8] = {0.f, 0.f, 0.f, 0.f, 0.f, 0.f, 0.f, 0.f};
    union U8 { uint4 u; __half2 h2[4]; };
    int e = beg + g;
    for (; e + EPW < end; e += 2 * EPW) {
        int s0 = col[e], s1 = col[e + EPW];
        U8 u0, u1;
        u0.u = h8[(size_t)s0 * L + li];
        u1.u = h8[(size_t)s1 * L + li];
        float w0 = NSLOAD ? ns[s0] : 1.f;
        float w1 = NSLOAD ? ns[s1] : 1.f;
#pragma unroll
        for (int p = 0; p < 4; p++) {
            float2 f0 = __half22float2(u0.h2[p]);
            float2 f1 = __half22float2(u1.h2[p]);
            if (NSLOAD) {
                a0[2 * p] = fmaf(w0, f0.x, a0[2 * p]);
                a0[2 * p + 1] = fmaf(w0, f0.y, a0[2 * p + 1]);
                a1[2 * p] = fmaf(w1, f1.x, a1[2 * p]);
                a1[2 * p + 1] = fmaf(w1, f1.y, a1[2 * p + 1]);
            } else {
                a0[2 * p] += f0.x;
                a0[2 * p + 1] += f0.y;
                a1[2 * p] += f1.x;
                a1[2 * p + 1] += f1.y;
            }
        }
    }
    if (e < end) {
        int s = col[e];
        U8 u0;
        u0.u = h8[(size_t)s * L + li];
        float w0 = NSLOAD ? ns[s] : 1.f;
#pragma unroll
        for (int p = 0; p < 4; p++) {
            float2 f0 = __half22float2(u0.h2[p]);
            if (NSLOAD) {
                a0[2 * p] = fmaf(w0, f0.x, a0[2 * p]);
                a0[2 * p + 1] = fmaf(w0, f0.y, a0[2 * p + 1]);
            } else {
                a0[2 * p] += f0.x;
                a0[2 * p + 1] += f0.y;
            }
        }
    }
#pragma unroll
    for (int j = 0; j < 8; j++) {
        float v = a0[j] + a1[j];
#pragma unroll
        for (int off = 32; off >= L; off >>= 1) v += __shfl_xor(v, off);
        a0[j] = v;
    }
    if (lane < L) {
        float w = nd[node];
#pragma unroll
        for (int j = 0; j < 8; j++) a0[j] *= w;
        if (EPI == 1) {
            float sc = ns[node];
#pragma unroll
            for (int j = 0; j < 8; j++)
                a0[j] = fmaxf(a0[j] + bias[li * 8 + j], 0.f) * sc;
        } else if (EPI == 2) {
#pragma unroll
            for (int j = 0; j < 8; j++) a0[j] += bias[li * 8 + j];
        }
        if (OUTH) {
            union { uint4 u; __half hh[8]; } cv;
#pragma unroll
            for (int j = 0; j < 8; j++) cv.hh[j] = __float2half(a0[j]);
            ((uint4*)out)[(size_t)node * L + li] = cv.u;
        } else {
            float4* o4 = (float4*)out;
            o4[(size_t)node * (CH / 4) + li * 2] = make_float4(a0[0], a0[1], a0[2], a0[3]);
            o4[(size_t)node * (CH / 4) + li * 2 + 1] = make_float4(a0[4], a0[5], a0[6], a0[7]);
        }
    }
}

// ---------------- standalone dot2 GEMM (64-row tile) ----------------

template <int TN, bool BIAS, bool RELU, bool SCALE, typename IT, typename OT>
__global__ __launch_bounds__(256) void gemm_h_kernel(
    const IT* __restrict__ A, const h2_t* __restrict__ Wt2,
    const float* __restrict__ bias, const float* __restrict__ rowscale,
    OT* __restrict__ out, int M, int K) {
    __shared__ h2_t As2[16 * 68];
    __shared__ h2_t Bs2[16 * TN];
    gemm_block_h<TN, BIAS, RELU, SCALE, IT, OT>(A, Wt2, bias, rowscale, out, M, K,
                                                blockIdx.x * 64, As2, Bs2);
}

// ---------------- launch ----------------

extern "C" void kernel_launch(void* const* d_in, const int* in_sizes, int n_in,
                              void* d_out, int out_size, void* d_ws, size_t ws_size,
                              hipStream_t stream) {
    const float* feat0 = (const float*)d_in[0];
    const float* feat1 = (const float*)d_in[1];
    const float* feat2 = (const float*)d_in[2];
    const float* W0 = (const float*)d_in[3];
    const float* b0 = (const float*)d_in[4];
    const float* W1 = (const float*)d_in[5];
    const float* b1 = (const float*)d_in[6];
    const float* W2 = (const float*)d_in[7];
    const float* b2 = (const float*)d_in[8];
    const float* bias_l0 = (const float*)d_in[9];
    const float* W_l1 = (const float*)d_in[10];
    const float* b_l1 = (const float*)d_in[11];
    const float* W_l2 = (const float*)d_in[12];
    const float* b_l2 = (const float*)d_in[13];
    const int* src = (const int*)d_in[14];
    const int* dst = (const int*)d_in[15];
    float* out = (float*)d_out;

    char* ws = (char*)d_ws;
    size_t off = 0;
    auto alloc = [&](size_t bytes) {
        size_t cur = off;
        off += (bytes + 255) & ~(size_t)255;
        return cur;
    };
    size_t Wt2_off = alloc((size_t)WT2_TOTAL * 4);      // interleaved half2 weights
    size_t h0h_off = alloc((size_t)N_NODES * H_ * 2);   // proj out (fp16)
    size_t h1h_off = alloc((size_t)N_NODES * H_ * 2);   // agg0 out (fp16)
    size_t hAh_off = alloc((size_t)N_NODES * H_ * 2);   // agg1 out (fp16)
    size_t hBh_off = alloc((size_t)N_NODES * H_ * 2);   // gemm1 out (fp16)
    size_t h2h_off = alloc((size_t)N_NODES * C_ * 2);   // gemm2 out (fp16)
    size_t cnt_off = alloc((size_t)N_NODES * 4);        // zeroed each call
    size_t degO_off = alloc((size_t)N_NODES * 4);       // zeroed each call
    size_t ns_off = alloc((size_t)N_NODES * 4);
    size_t nd_off = alloc((size_t)N_NODES * 4);
    size_t rowptr_off = alloc((size_t)(N_NODES + 1) * 4);
    size_t rank_off = alloc((size_t)E_EDGES * 4);
    size_t col_off = alloc((size_t)E_EDGES * 4);
    size_t pre_off = alloc((size_t)N_NODES * 4);
    size_t bsum_off = alloc((size_t)SB * 4);
    size_t boff_off = alloc((size_t)SB * 4);

    h2_t* Wt2 = (h2_t*)(ws + Wt2_off);
    __half* h0h = (__half*)(ws + h0h_off);
    __half* h1h = (__half*)(ws + h1h_off);
    __half* hAh = (__half*)(ws + hAh_off);
    __half* hBh = (__half*)(ws + hBh_off);
    __half* h2h = (__half*)(ws + h2h_off);
    int* cnt = (int*)(ws + cnt_off);
    int* degO = (int*)(ws + degO_off);
    float* ns = (float*)(ws + ns_off);
    float* nd = (float*)(ws + nd_off);
    int* rowptr = (int*)(ws + rowptr_off);
    int* rank = (int*)(ws + rank_off);
    int* col = (int*)(ws + col_off);
    int* pre = (int*)(ws + pre_off);
    int* bsum = (int*)(ws + bsum_off);
    int* boff = (int*)(ws + boff_off);

    hipMemsetAsync(ws + cnt_off, 0, ns_off - cnt_off, stream);  // cnt + degO

    // W -> interleaved half2 (one-time, tiny)
    wt2_kernel<<<(WT2_TOTAL + 255) / 256, 256, 0, stream>>>(W0, W1, W2, W_l1, W_l2, Wt2);
    // K1: dot2 projections || rank
    k1_proj_rank<<<PB_TOTAL + EB, 256, 0, stream>>>(
        feat0, feat1, feat2, Wt2, b0, b1, b2, h0h, src, dst, cnt, degO, rank);
    // hierarchical scan; norms + col-fill merged into the third stage
    scan1_kernel<<<SB, 256, 0, stream>>>(cnt, pre, bsum);
    scan2_kernel<<<1, 256, 0, stream>>>(bsum, boff, rowptr);
    scan3_fill_kernel<<<SB + EB, 256, 0, stream>>>(
        cnt, degO, pre, boff, rowptr, ns, nd, src, dst, rank, col);

    const int AGB = (N_NODES + 3) / 4;
    // layer 0: fp16 gather (ns-weighted), +bias, relu, *ns -> fp16 h1
    agg_h_kernel<128, 1, 1, 1><<<AGB, 256, 0, stream>>>(h0h, rowptr, col, ns, nd, bias_l0, h1h);
    // layer 1: fp16 gather (pre-scaled) -> fp16 hAh; dot2 GEMM + bias + relu, *ns
    agg_h_kernel<128, 0, 0, 1><<<AGB, 256, 0, stream>>>(h1h, rowptr, col, ns, nd, nullptr, hAh);
    gemm_h_kernel<128, true, true, true, __half, __half><<<(N_NODES + 63) / 64, 256, 0, stream>>>(
        hAh, Wt2 + WT2_L1, b_l1, ns, hBh, N_NODES, 128);
    // layer 2 reordered: dot2 GEMM first (no bias), then 64-ch fp16 agg + bias
    gemm_h_kernel<64, false, false, false, __half, __half><<<(N_NODES + 63) / 64, 256, 0, stream>>>(
        hBh, Wt2 + WT2_L2, nullptr, nullptr, h2h, N_NODES, 128);
    agg_h_kernel<64, 0, 2, 0><<<AGB, 256, 0, stream>>>(h2h, rowptr, col, ns, nd, b_l2, out);
}